// Round 12
// baseline (166.687 us; speedup 1.0000x reference)
//
#include <hip/hip_runtime.h>
#include <math.h>

// ---------------------------------------------------------------------------
// SparseMHA, round 12:
//   prep: W^T bf16 + bias concat + CSR row_ptr (1 kernel)
//   gemm<0>: A reg-staged from f32 h with inline bf16 cvt (no convert pass);
//     -> qb[n][256] bf16 (scaled q)
//     -> kv[n] 512B rows: k fp8 e4m3 [0,256) + v uint8 biased [256,512)
//     -> vscale[n][8] f32 (separate, L2-resident)
//   fused_attn: gathers 512B/edge (aligned) + L2-hit scale; lane-local p;
//     depth-2 pipeline; int8 dequant with -128*sum(p*scale) correction
//   gemm<1>: out = aggb @ Wo + bo (f32)
// ---------------------------------------------------------------------------

typedef __attribute__((ext_vector_type(8))) short bf16x8;
typedef __attribute__((ext_vector_type(4))) float f32x4;
typedef __attribute__((ext_vector_type(2))) float f32x2;

__device__ __forceinline__ ushort f2bf(float f) {           // RNE f32->bf16
    uint u = __float_as_uint(f);
    u += 0x7fffu + ((u >> 16) & 1u);
    return (ushort)(u >> 16);
}
__device__ __forceinline__ float bflo(uint u) { return __uint_as_float(u << 16); }
__device__ __forceinline__ float bfhi(uint u) { return __uint_as_float(u & 0xffff0000u); }

__device__ __forceinline__ uchar f2fp8(float f) {
    return (uchar)(__builtin_amdgcn_cvt_pk_fp8_f32(f, f, 0, false) & 0xff);
}
__device__ __forceinline__ void fp8x4_to_f32(uint u, float* f) {
    f32x2 lo = __builtin_amdgcn_cvt_pk_f32_fp8(u, false);
    f32x2 hi = __builtin_amdgcn_cvt_pk_f32_fp8(u, true);
    f[0] = lo[0]; f[1] = lo[1]; f[2] = hi[0]; f[3] = hi[1];
}

__device__ __forceinline__ void load_lds16(const void* g, void* l) {
    __builtin_amdgcn_global_load_lds(
        (const __attribute__((address_space(1))) void*)g,
        (__attribute__((address_space(3))) void*)l, 16, 0, 0);
}

// All prep in one launch: grid (257, 5).
__global__ __launch_bounds__(256) void prep(
    const float* __restrict__ Wq, const float* __restrict__ Wk,
    const float* __restrict__ Wv, const float* __restrict__ Wo,
    const float* __restrict__ bq, const float* __restrict__ bk,
    const float* __restrict__ bv,
    const int* __restrict__ row, int* __restrict__ row_ptr, int n, int E,
    ushort* __restrict__ Wall, ushort* __restrict__ Wot,
    float* __restrict__ ball)
{
    int m = blockIdx.y;
    if (m == 4) {
        int i = blockIdx.x * 256 + threadIdx.x;
        if (i > n) return;
        int lo = 0, hi = E;
        while (lo < hi) {
            int mid = (lo + hi) >> 1;
            if (row[mid] < i) lo = mid + 1; else hi = mid;
        }
        row_ptr[i] = lo;
        return;
    }
    if (blockIdx.x < 256) {
        int idx = blockIdx.x * 256 + threadIdx.x;   // idx = k*256 + nn
        int k = idx >> 8, nn = idx & 255;
        if (m < 3) {
            const float* W = m == 0 ? Wq : (m == 1 ? Wk : Wv);
            Wall[((size_t)m * 256 + nn) * 256 + k] = f2bf(W[idx]);
        } else {
            Wot[nn * 256 + k] = f2bf(Wo[idx]);
        }
    } else if (m < 3) {
        int i = threadIdx.x;
        ball[m * 256 + i] = (m == 0 ? bq : (m == 1 ? bk : bv))[i];
    }
}

// ---------------------------------------------------------------------------
// LDS-staged MFMA GEMM (m97 structure), 128x128 tiles, grid (6|2, mtiles).
// MODE 0 (QKV): A = f32 h, reg-staged with inline bf16 cvt. Col tile 0,1 ->
//   qb bf16 (scaled); 2,3 -> kv k fp8; 4,5 -> kv v int8 + vscale.
// MODE 1 (out): A = bf16 agg via global_load_lds; f32 direct stores.
// ---------------------------------------------------------------------------
template<int MODE>
__global__ __launch_bounds__(256) void gemm_mfma_lds(
    const void* __restrict__ Av, const ushort* __restrict__ Wt,
    const float* __restrict__ bias, ushort* __restrict__ qb,
    uchar* __restrict__ kv, float* __restrict__ vscale,
    float* __restrict__ outf, int n, float scale)
{
    __shared__ ushort SH[2 * 128 * 64];          // As | Bs, reused by epilogue
    ushort* As = SH;
    ushort* Bs = SH + 128 * 64;

    const int nwg = gridDim.x * gridDim.y;
    const int orig = blockIdx.y * gridDim.x + blockIdx.x;
    const int xcd = orig & 7, rnd = orig >> 3;
    const int q8 = nwg >> 3, r8 = nwg & 7;
    const int wgid = (xcd < r8 ? xcd * (q8 + 1) : r8 * (q8 + 1) + (xcd - r8) * q8) + rnd;
    const int tx = wgid % gridDim.x;
    const int ty = wgid / gridDim.x;

    const int tid = threadIdx.x;
    const int lane = tid & 63;
    const int wave = tid >> 6;
    const int col0 = tx * 128;
    const int row0 = ty * 128;
    const int fr = lane & 15;
    const int kg = lane >> 4;
    const int wr = (wave >> 1) * 64;
    const int wc = (wave & 1) * 64;

    f32x4 acc[4][4] = {};

    const int srow = tid >> 3;
    const int sc8 = tid & 7;

    for (int kt = 0; kt < 4; ++kt) {
        #pragma unroll
        for (int it = 0; it < 4; ++it) {
            int r = srow + it * 32;
            int chunk = sc8 ^ (r & 7);
            int ar = row0 + r; ar = ar < n ? ar : n - 1;
            if constexpr (MODE == 0) {
                // f32 source: 32B of h -> 8 bf16 -> ds_write 16B
                const float4* hp = (const float4*)((const char*)Av +
                    (size_t)ar * 1024 + kt * 256 + chunk * 32);
                float4 f0 = hp[0], f1 = hp[1];
                uint4 w;
                w.x = (uint)f2bf(f0.x) | ((uint)f2bf(f0.y) << 16);
                w.y = (uint)f2bf(f0.z) | ((uint)f2bf(f0.w) << 16);
                w.z = (uint)f2bf(f1.x) | ((uint)f2bf(f1.y) << 16);
                w.w = (uint)f2bf(f1.z) | ((uint)f2bf(f1.w) << 16);
                *(uint4*)((char*)As + (it * 256 + tid) * 16) = w;
            } else {
                load_lds16((const char*)Av + (size_t)ar * 512 + kt * 128 + chunk * 16,
                           (char*)As + (it * 256 + tid) * 16);
            }
            load_lds16((const char*)Wt + (size_t)(col0 + srow + it * 32) * 512 +
                           kt * 128 + chunk * 16,
                       (char*)Bs + (it * 256 + tid) * 16);
        }
        __syncthreads();

        #pragma unroll
        for (int ks = 0; ks < 2; ++ks) {
            bf16x8 a[4], b[4];
            #pragma unroll
            for (int i = 0; i < 4; ++i) {
                int r = wr + i * 16 + fr;
                int chunk = (ks * 4 + kg) ^ (r & 7);
                a[i] = *(const bf16x8*)((const char*)As + r * 128 + chunk * 16);
            }
            #pragma unroll
            for (int j = 0; j < 4; ++j) {
                int c = wc + j * 16 + fr;
                int chunk = (ks * 4 + kg) ^ (c & 7);
                b[j] = *(const bf16x8*)((const char*)Bs + c * 128 + chunk * 16);
            }
            #pragma unroll
            for (int i = 0; i < 4; ++i)
                #pragma unroll
                for (int j = 0; j < 4; ++j)
                    acc[i][j] = __builtin_amdgcn_mfma_f32_16x16x32_bf16(
                        a[i], b[j], acc[i][j], 0, 0, 0);
        }
        __syncthreads();
    }

    if constexpr (MODE == 1) {
        #pragma unroll
        for (int j = 0; j < 4; ++j) {
            int gcol = col0 + wc + j * 16 + fr;
            float bj = bias[gcol];
            #pragma unroll
            for (int i = 0; i < 4; ++i) {
                #pragma unroll
                for (int r = 0; r < 4; ++r) {
                    int grow = row0 + wr + i * 16 + kg * 4 + r;
                    if (grow >= n) continue;
                    outf[(size_t)grow * 256 + gcol] = acc[i][j][r] + bj;
                }
            }
        }
        return;
    }

    // ---- MODE 0 epilogue: pack to LDS, then coalesced stores ----
    char* sb = (char*)SH;
    const bool isf8 = (col0 >= 256 && col0 < 512);   // k tile -> fp8
    const bool isv  = (col0 >= 512);                 // v tile -> int8+scale
    const float sc = (col0 < 256) ? scale : 1.f;

    #pragma unroll
    for (int j = 0; j < 4; ++j) {
        int cw = wc + j * 16 + fr;                   // local col 0..127
        float bj = bias[col0 + cw];
        #pragma unroll
        for (int i = 0; i < 4; ++i) {
            #pragma unroll
            for (int r2 = 0; r2 < 4; ++r2) {
                int lrow = wr + i * 16 + kg * 4 + r2;
                float val = (acc[i][j][r2] + bj) * sc;
                if (isf8) {
                    int u = cw >> 4;
                    sb[lrow * 128 + ((u ^ (lrow & 7)) << 4) + (cw & 15)] = f2fp8(val);
                } else {
                    int u = cw >> 3;
                    *(ushort*)(sb + lrow * 256 + ((u ^ (lrow & 7)) << 4) +
                               ((cw & 7) << 1)) = f2bf(val);
                }
            }
        }
    }
    __syncthreads();

    if (isf8) {
        int seg = col0 - 256;     // 0 or 128
        #pragma unroll
        for (int pass = 0; pass < 4; ++pass) {
            int g = pass * 256 + tid;
            int lrow = g >> 3, u = g & 7;
            uint4 d = *(const uint4*)(sb + lrow * 128 + ((u ^ (lrow & 7)) << 4));
            int grow = row0 + lrow;
            if (grow < n)
                *(uint4*)((char*)kv + (size_t)grow * 512 + seg + u * 16) = d;
        }
    } else if (isv) {
        // per-(row,head) int8 quant: 128 rows x 4 heads = 512 pairs, 2 passes
        int vseg = col0 - 512;                       // 0 or 128
        #pragma unroll
        for (int pass = 0; pass < 2; ++pass) {
            int t = pass * 256 + tid;
            int lrow = t >> 2, hh = t & 3;
            float vals[32];
            #pragma unroll
            for (int uu = 0; uu < 4; ++uu) {
                int u = hh * 4 + uu;
                uint4 d = *(const uint4*)(sb + lrow * 256 + ((u ^ (lrow & 7)) << 4));
                vals[uu*8+0] = bflo(d.x); vals[uu*8+1] = bfhi(d.x);
                vals[uu*8+2] = bflo(d.y); vals[uu*8+3] = bfhi(d.y);
                vals[uu*8+4] = bflo(d.z); vals[uu*8+5] = bfhi(d.z);
                vals[uu*8+6] = bflo(d.w); vals[uu*8+7] = bfhi(d.w);
            }
            float mx = 0.f;
            #pragma unroll
            for (int i = 0; i < 32; ++i) mx = fmaxf(mx, fabsf(vals[i]));
            float inv = mx > 0.f ? 127.f / mx : 0.f;
            float scl = mx > 0.f ? mx * (1.f / 127.f) : 0.f;
            uint pk[8];
            #pragma unroll
            for (int w = 0; w < 8; ++w) {
                uint b0 = (uint)(__float2int_rn(vals[w*4+0] * inv) + 128);
                uint b1 = (uint)(__float2int_rn(vals[w*4+1] * inv) + 128);
                uint b2 = (uint)(__float2int_rn(vals[w*4+2] * inv) + 128);
                uint b3 = (uint)(__float2int_rn(vals[w*4+3] * inv) + 128);
                pk[w] = b0 | (b1 << 8) | (b2 << 16) | (b3 << 24);
            }
            int grow = row0 + lrow;
            if (grow < n) {
                char* dst = (char*)kv + (size_t)grow * 512 + 256 + vseg + hh * 32;
                *(uint4*)dst        = make_uint4(pk[0], pk[1], pk[2], pk[3]);
                *(uint4*)(dst + 16) = make_uint4(pk[4], pk[5], pk[6], pk[7]);
                vscale[(size_t)grow * 8 + (vseg >> 5) + hh] = scl;
            }
        }
    } else {
        // q: 128 rows x 256B: 8 passes; 16 lanes = one 256B row segment
        #pragma unroll
        for (int pass = 0; pass < 8; ++pass) {
            int g = pass * 256 + tid;
            int lrow = g >> 4, u = g & 15;
            uint4 d = *(const uint4*)(sb + lrow * 256 + ((u ^ (lrow & 7)) << 4));
            int grow = row0 + lrow;
            if (grow < n)
                *(uint4*)((char*)qb + (size_t)grow * 512 + col0 * 2 + u * 16) = d;
        }
    }
}

// Fused SDDMM + softmax + SpMM. One wave per dst node.
// kv row (512B): k fp8 [0,256) + v uint8 biased [256,512); vscale separate.
__global__ __launch_bounds__(256) void fused_attn(
    const ushort* __restrict__ qb, const uchar* __restrict__ kv,
    const float* __restrict__ vscale, const int* __restrict__ col,
    const int* __restrict__ row_ptr, ushort* __restrict__ agg, int n)
{
    int node = blockIdx.x * 4 + (threadIdx.x >> 6);
    if (node >= n) return;
    int lane = threadIdx.x & 63;
    int p0 = row_ptr[node], p1 = row_ptr[node + 1];

    const int slot = lane >> 4;          // 0..3 edge slot
    const int l16 = lane & 15;           // covers dims [l16*16, l16*16+16)
    const int qoff = l16 * 32;

    float qf[16];
    {
        const char* qbp = (const char*)qb + (size_t)node * 512 + qoff;
        uint4 q0 = *(const uint4*)qbp;
        uint4 q1 = *(const uint4*)(qbp + 16);
        qf[0] = bflo(q0.x); qf[1] = bfhi(q0.x);
        qf[2] = bflo(q0.y); qf[3] = bfhi(q0.y);
        qf[4] = bflo(q0.z); qf[5] = bfhi(q0.z);
        qf[6] = bflo(q0.w); qf[7] = bfhi(q0.w);
        qf[8] = bflo(q1.x); qf[9] = bfhi(q1.x);
        qf[10] = bflo(q1.y); qf[11] = bfhi(q1.y);
        qf[12] = bflo(q1.z); qf[13] = bfhi(q1.z);
        qf[14] = bflo(q1.w); qf[15] = bfhi(q1.w);
    }

    float denom = 0.f;
    float cacc = 0.f;                    // sum of p*scale (for -128 correction)
    float acc[16] = {};

#define ISSUE(IDX, K, V, S)                                                    \
    do {                                                                       \
        int src_ = __shfl(cl, (IDX));                                          \
        const char* b_ = (const char*)kv + (size_t)src_ * 512;                 \
        K = *(const uint4*)(b_ + l16 * 16);                                    \
        V = *(const uint4*)(b_ + 256 + l16 * 16);                              \
        S = vscale[(size_t)src_ * 8 + (l16 >> 1)];                             \
    } while (0)

#define CONSUME(VALID, K, V, S)                                                \
    do {                                                                       \
        float kf_[16];                                                         \
        fp8x4_to_f32(K.x, kf_); fp8x4_to_f32(K.y, kf_ + 4);                    \
        fp8x4_to_f32(K.z, kf_ + 8); fp8x4_to_f32(K.w, kf_ + 12);               \
        float sp_ = 0.f;                                                       \
        _Pragma("unroll")                                                      \
        for (int i_ = 0; i_ < 16; ++i_) sp_ = fmaf(qf[i_], kf_[i_], sp_);      \
        float s_ = sp_ + __shfl_xor(sp_, 1);                                   \
        float p_ = (VALID) ? __expf(s_) : 0.f;                                 \
        denom += p_;                                                           \
        float ps_ = p_ * (S);                                                  \
        cacc += ps_;                                                           \
        uint w_;                                                               \
        w_ = V.x;                                                              \
        acc[0]  = fmaf(ps_, (float)(w_ & 0xff),         acc[0]);               \
        acc[1]  = fmaf(ps_, (float)((w_ >> 8) & 0xff),  acc[1]);               \
        acc[2]  = fmaf(ps_, (float)((w_ >> 16) & 0xff), acc[2]);               \
        acc[3]  = fmaf(ps_, (float)(w_ >> 24),          acc[3]);               \
        w_ = V.y;                                                              \
        acc[4]  = fmaf(ps_, (float)(w_ & 0xff),         acc[4]);               \
        acc[5]  = fmaf(ps_, (float)((w_ >> 8) & 0xff),  acc[5]);               \
        acc[6]  = fmaf(ps_, (float)((w_ >> 16) & 0xff), acc[6]);               \
        acc[7]  = fmaf(ps_, (float)(w_ >> 24),          acc[7]);               \
        w_ = V.z;                                                              \
        acc[8]  = fmaf(ps_, (float)(w_ & 0xff),         acc[8]);               \
        acc[9]  = fmaf(ps_, (float)((w_ >> 8) & 0xff),  acc[9]);               \
        acc[10] = fmaf(ps_, (float)((w_ >> 16) & 0xff), acc[10]);              \
        acc[11] = fmaf(ps_, (float)(w_ >> 24),          acc[11]);              \
        w_ = V.w;                                                              \
        acc[12] = fmaf(ps_, (float)(w_ & 0xff),         acc[12]);              \
        acc[13] = fmaf(ps_, (float)((w_ >> 8) & 0xff),  acc[13]);              \
        acc[14] = fmaf(ps_, (float)((w_ >> 16) & 0xff), acc[14]);              \
        acc[15] = fmaf(ps_, (float)(w_ >> 24),          acc[15]);              \
    } while (0)

    for (int bbase = p0; bbase < p1; bbase += 64) {
        int bd = min(64, p1 - bbase);
        int cl = (lane < bd) ? col[bbase + lane] : 0;
        int nch = (bd + 3) >> 2;

        uint4 kA, vA, kB, vB; float sA, sB;
        ISSUE(slot, kA, vA, sA);
        int c = 0;
        for (;;) {
            if (c + 1 < nch) ISSUE((c + 1) * 4 + slot, kB, vB, sB);
            CONSUME(c * 4 + slot < bd, kA, vA, sA);
            if (++c >= nch) break;
            if (c + 1 < nch) ISSUE((c + 1) * 4 + slot, kA, vA, sA);
            CONSUME(c * 4 + slot < bd, kB, vB, sB);
            if (++c >= nch) break;
        }
    }
#undef ISSUE
#undef CONSUME

    // undo the +128 bias, then reduce over the 4 slots
    #pragma unroll
    for (int i = 0; i < 16; ++i) acc[i] = fmaf(-128.f, cacc, acc[i]);
    #pragma unroll
    for (int i = 0; i < 16; ++i) {
        acc[i] += __shfl_xor(acc[i], 16);
        acc[i] += __shfl_xor(acc[i], 32);
    }
    denom += __shfl_xor(denom, 16);
    denom += __shfl_xor(denom, 32);

    if (slot == 0) {
        float inv = denom > 0.f ? 1.f / denom : 0.f;
        uint o[8];
        #pragma unroll
        for (int i = 0; i < 8; ++i)
            o[i] = (uint)f2bf(acc[2 * i] * inv) |
                   ((uint)f2bf(acc[2 * i + 1] * inv) << 16);
        char* ob = (char*)agg + (size_t)node * 512 + qoff;
        *(uint4*)ob        = make_uint4(o[0], o[1], o[2], o[3]);
        *(uint4*)(ob + 16) = make_uint4(o[4], o[5], o[6], o[7]);
    }
}

extern "C" void kernel_launch(void* const* d_in, const int* in_sizes, int n_in,
                              void* d_out, int out_size, void* d_ws, size_t ws_size,
                              hipStream_t stream)
{
    const float* h  = (const float*)d_in[0];
    const int*   row = (const int*)d_in[1];
    const int*   col = (const int*)d_in[2];
    const float* Wq = (const float*)d_in[3];
    const float* bq = (const float*)d_in[4];
    const float* Wk = (const float*)d_in[5];
    const float* bk = (const float*)d_in[6];
    const float* Wv = (const float*)d_in[7];
    const float* bv = (const float*)d_in[8];
    const float* Wo = (const float*)d_in[9];
    const float* bo = (const float*)d_in[10];
    float* out = (float*)d_out;

    const int n = in_sizes[0] / 256;
    const int E = in_sizes[1];
    const size_t NC = (size_t)n * 256;

    char* base = (char*)d_ws;
    ushort* qbb    = (ushort*)(base);                            // NC*2 B
    uchar*  kv     = (uchar*)(base + NC * 2);                    // n*512 B
    float*  vscale = (float*)(base + NC * 4);                    // n*32 B
    ushort* aggb   = (ushort*)(base + NC * 4 + (size_t)n * 32);  // NC*2
    ushort* Wall   = (ushort*)(base + NC * 6 + (size_t)n * 32);  // 384KB
    ushort* Wot    = Wall + 768 * 256;                           // 128KB
    float*  ball   = (float*)(Wot + 65536);                      // 3KB
    int* row_ptr   = (int*)(ball + 768);

    const float scaling = 0.17677669529663687f;  // 32^-0.5

    dim3 blk(256);
    prep<<<dim3(257, 5), blk, 0, stream>>>(Wq, Wk, Wv, Wo, bq, bk, bv,
                                           row, row_ptr, n, E,
                                           Wall, Wot, ball);

    const int mtiles = (n + 127) / 128;
    gemm_mfma_lds<0><<<dim3(6, mtiles), blk, 0, stream>>>(
        h, Wall, ball, qbb, kv, vscale, nullptr, n, scaling);

    fused_attn<<<dim3((n + 3) / 4), blk, 0, stream>>>(
        qbb, kv, vscale, col, row_ptr, aggb, n);

    gemm_mfma_lds<1><<<dim3(2, mtiles), blk, 0, stream>>>(
        aggb, Wot, bo, nullptr, nullptr, nullptr, out, n, 1.f);
}

// Round 13
// 156.914 us; speedup vs baseline: 1.0623x; 1.0623x over previous
//
#include <hip/hip_runtime.h>
#include <math.h>

// ---------------------------------------------------------------------------
// SparseMHA, round 13 (recombination of proven halves):
//   prep: W^T bf16 + bias concat + CSR row_ptr (1 kernel)         [round 11]
//   convert_bf16: h -> hb                                          [round 11]
//   gemm<0>: hb via global_load_lds (async staging)                [round 11]
//     -> qb[n][256] bf16 (scaled q)
//     -> kv[n] 512B rows: k fp8 e4m3 [0,256) + v uint8 [256,512)   [round 12]
//     -> vscale[n][8] f32 (separate, L2-resident)                  [round 12]
//   fused_attn: 512B/edge aligned gathers + L2 scale               [round 12]
//   gemm<1>: out = aggb @ Wo + bo (f32)
// ---------------------------------------------------------------------------

typedef __attribute__((ext_vector_type(8))) short bf16x8;
typedef __attribute__((ext_vector_type(4))) float f32x4;
typedef __attribute__((ext_vector_type(2))) float f32x2;

__device__ __forceinline__ ushort f2bf(float f) {           // RNE f32->bf16
    uint u = __float_as_uint(f);
    u += 0x7fffu + ((u >> 16) & 1u);
    return (ushort)(u >> 16);
}
__device__ __forceinline__ float bflo(uint u) { return __uint_as_float(u << 16); }
__device__ __forceinline__ float bfhi(uint u) { return __uint_as_float(u & 0xffff0000u); }

__device__ __forceinline__ uchar f2fp8(float f) {
    return (uchar)(__builtin_amdgcn_cvt_pk_fp8_f32(f, f, 0, false) & 0xff);
}
__device__ __forceinline__ void fp8x4_to_f32(uint u, float* f) {
    f32x2 lo = __builtin_amdgcn_cvt_pk_f32_fp8(u, false);
    f32x2 hi = __builtin_amdgcn_cvt_pk_f32_fp8(u, true);
    f[0] = lo[0]; f[1] = lo[1]; f[2] = hi[0]; f[3] = hi[1];
}

__device__ __forceinline__ void load_lds16(const void* g, void* l) {
    __builtin_amdgcn_global_load_lds(
        (const __attribute__((address_space(1))) void*)g,
        (__attribute__((address_space(3))) void*)l, 16, 0, 0);
}

// f32 -> bf16 elementwise (h)
__global__ __launch_bounds__(256) void convert_bf16(
    const float* __restrict__ in, ushort* __restrict__ out, size_t nelem)
{
    size_t i = ((size_t)blockIdx.x * 256 + threadIdx.x) * 4;
    if (i >= nelem) return;
    float4 v = *(const float4*)(in + i);
    *(ushort4*)(out + i) = make_ushort4(f2bf(v.x), f2bf(v.y), f2bf(v.z), f2bf(v.w));
}

// All prep in one launch: grid (257, 5).
//  y<4,  x<256 : convert W_y transposed -> bf16 (y=0..2 Wall concat, y=3 Wot)
//  y<3,  x==256: bias concat
//  y==4        : CSR row_ptr from sorted row[] (lower_bound)
__global__ __launch_bounds__(256) void prep(
    const float* __restrict__ Wq, const float* __restrict__ Wk,
    const float* __restrict__ Wv, const float* __restrict__ Wo,
    const float* __restrict__ bq, const float* __restrict__ bk,
    const float* __restrict__ bv,
    const int* __restrict__ row, int* __restrict__ row_ptr, int n, int E,
    ushort* __restrict__ Wall, ushort* __restrict__ Wot,
    float* __restrict__ ball)
{
    int m = blockIdx.y;
    if (m == 4) {
        int i = blockIdx.x * 256 + threadIdx.x;
        if (i > n) return;
        int lo = 0, hi = E;
        while (lo < hi) {
            int mid = (lo + hi) >> 1;
            if (row[mid] < i) lo = mid + 1; else hi = mid;
        }
        row_ptr[i] = lo;
        return;
    }
    if (blockIdx.x < 256) {
        int idx = blockIdx.x * 256 + threadIdx.x;   // idx = k*256 + nn
        int k = idx >> 8, nn = idx & 255;
        if (m < 3) {
            const float* W = m == 0 ? Wq : (m == 1 ? Wk : Wv);
            Wall[((size_t)m * 256 + nn) * 256 + k] = f2bf(W[idx]);
        } else {
            Wot[nn * 256 + k] = f2bf(Wo[idx]);
        }
    } else if (m < 3) {
        int i = threadIdx.x;
        ball[m * 256 + i] = (m == 0 ? bq : (m == 1 ? bk : bv))[i];
    }
}

// ---------------------------------------------------------------------------
// LDS-staged MFMA GEMM (m97 structure), 128x128 tiles, grid (6|2, mtiles).
// Both A and B staged via async global_load_lds (bf16 sources).
// MODE 0 (QKV): col tile 0,1 -> qb bf16 (scaled); 2,3 -> kv k fp8;
//               4,5 -> kv v int8 + vscale. Epilogue via LDS bounce.
// MODE 1 (out): f32 direct stores.
// ---------------------------------------------------------------------------
template<int MODE>
__global__ __launch_bounds__(256) void gemm_mfma_lds(
    const ushort* __restrict__ A, const ushort* __restrict__ Wt,
    const float* __restrict__ bias, ushort* __restrict__ qb,
    uchar* __restrict__ kv, float* __restrict__ vscale,
    float* __restrict__ outf, int n, float scale)
{
    __shared__ ushort SH[2 * 128 * 64];          // As | Bs, reused by epilogue
    ushort* As = SH;
    ushort* Bs = SH + 128 * 64;

    const int nwg = gridDim.x * gridDim.y;
    const int orig = blockIdx.y * gridDim.x + blockIdx.x;
    const int xcd = orig & 7, rnd = orig >> 3;
    const int q8 = nwg >> 3, r8 = nwg & 7;
    const int wgid = (xcd < r8 ? xcd * (q8 + 1) : r8 * (q8 + 1) + (xcd - r8) * q8) + rnd;
    const int tx = wgid % gridDim.x;
    const int ty = wgid / gridDim.x;

    const int tid = threadIdx.x;
    const int lane = tid & 63;
    const int wave = tid >> 6;
    const int col0 = tx * 128;
    const int row0 = ty * 128;
    const int fr = lane & 15;
    const int kg = lane >> 4;
    const int wr = (wave >> 1) * 64;
    const int wc = (wave & 1) * 64;

    f32x4 acc[4][4] = {};

    const int srow = tid >> 3;
    const int sc8 = tid & 7;

    for (int kt = 0; kt < 4; ++kt) {
        #pragma unroll
        for (int it = 0; it < 4; ++it) {
            int r = srow + it * 32;
            int chunk = sc8 ^ (r & 7);
            int ar = row0 + r; ar = ar < n ? ar : n - 1;
            load_lds16((const char*)A + (size_t)ar * 512 + kt * 128 + chunk * 16,
                       (char*)As + (it * 256 + tid) * 16);
            load_lds16((const char*)Wt + (size_t)(col0 + r) * 512 + kt * 128 + chunk * 16,
                       (char*)Bs + (it * 256 + tid) * 16);
        }
        __syncthreads();

        #pragma unroll
        for (int ks = 0; ks < 2; ++ks) {
            bf16x8 a[4], b[4];
            #pragma unroll
            for (int i = 0; i < 4; ++i) {
                int r = wr + i * 16 + fr;
                int chunk = (ks * 4 + kg) ^ (r & 7);
                a[i] = *(const bf16x8*)((const char*)As + r * 128 + chunk * 16);
            }
            #pragma unroll
            for (int j = 0; j < 4; ++j) {
                int c = wc + j * 16 + fr;
                int chunk = (ks * 4 + kg) ^ (c & 7);
                b[j] = *(const bf16x8*)((const char*)Bs + c * 128 + chunk * 16);
            }
            #pragma unroll
            for (int i = 0; i < 4; ++i)
                #pragma unroll
                for (int j = 0; j < 4; ++j)
                    acc[i][j] = __builtin_amdgcn_mfma_f32_16x16x32_bf16(
                        a[i], b[j], acc[i][j], 0, 0, 0);
        }
        __syncthreads();
    }

    if constexpr (MODE == 1) {
        #pragma unroll
        for (int j = 0; j < 4; ++j) {
            int gcol = col0 + wc + j * 16 + fr;
            float bj = bias[gcol];
            #pragma unroll
            for (int i = 0; i < 4; ++i) {
                #pragma unroll
                for (int r = 0; r < 4; ++r) {
                    int grow = row0 + wr + i * 16 + kg * 4 + r;
                    if (grow >= n) continue;
                    outf[(size_t)grow * 256 + gcol] = acc[i][j][r] + bj;
                }
            }
        }
        return;
    }

    // ---- MODE 0 epilogue: pack to LDS, then coalesced stores ----
    char* sb = (char*)SH;
    const bool isf8 = (col0 >= 256 && col0 < 512);   // k tile -> fp8
    const bool isv  = (col0 >= 512);                 // v tile -> int8+scale
    const float sc = (col0 < 256) ? scale : 1.f;

    #pragma unroll
    for (int j = 0; j < 4; ++j) {
        int cw = wc + j * 16 + fr;                   // local col 0..127
        float bj = bias[col0 + cw];
        #pragma unroll
        for (int i = 0; i < 4; ++i) {
            #pragma unroll
            for (int r2 = 0; r2 < 4; ++r2) {
                int lrow = wr + i * 16 + kg * 4 + r2;
                float val = (acc[i][j][r2] + bj) * sc;
                if (isf8) {
                    int u = cw >> 4;
                    sb[lrow * 128 + ((u ^ (lrow & 7)) << 4) + (cw & 15)] = f2fp8(val);
                } else {
                    int u = cw >> 3;
                    *(ushort*)(sb + lrow * 256 + ((u ^ (lrow & 7)) << 4) +
                               ((cw & 7) << 1)) = f2bf(val);
                }
            }
        }
    }
    __syncthreads();

    if (isf8) {
        int seg = col0 - 256;     // 0 or 128
        #pragma unroll
        for (int pass = 0; pass < 4; ++pass) {
            int g = pass * 256 + tid;
            int lrow = g >> 3, u = g & 7;
            uint4 d = *(const uint4*)(sb + lrow * 128 + ((u ^ (lrow & 7)) << 4));
            int grow = row0 + lrow;
            if (grow < n)
                *(uint4*)((char*)kv + (size_t)grow * 512 + seg + u * 16) = d;
        }
    } else if (isv) {
        // per-(row,head) int8 quant: 128 rows x 4 heads = 512 pairs, 2 passes
        int vseg = col0 - 512;                       // 0 or 128
        #pragma unroll
        for (int pass = 0; pass < 2; ++pass) {
            int t = pass * 256 + tid;
            int lrow = t >> 2, hh = t & 3;
            float vals[32];
            #pragma unroll
            for (int uu = 0; uu < 4; ++uu) {
                int u = hh * 4 + uu;
                uint4 d = *(const uint4*)(sb + lrow * 256 + ((u ^ (lrow & 7)) << 4));
                vals[uu*8+0] = bflo(d.x); vals[uu*8+1] = bfhi(d.x);
                vals[uu*8+2] = bflo(d.y); vals[uu*8+3] = bfhi(d.y);
                vals[uu*8+4] = bflo(d.z); vals[uu*8+5] = bfhi(d.z);
                vals[uu*8+6] = bflo(d.w); vals[uu*8+7] = bfhi(d.w);
            }
            float mx = 0.f;
            #pragma unroll
            for (int i = 0; i < 32; ++i) mx = fmaxf(mx, fabsf(vals[i]));
            float inv = mx > 0.f ? 127.f / mx : 0.f;
            float scl = mx > 0.f ? mx * (1.f / 127.f) : 0.f;
            uint pk[8];
            #pragma unroll
            for (int w = 0; w < 8; ++w) {
                uint b0 = (uint)(__float2int_rn(vals[w*4+0] * inv) + 128);
                uint b1 = (uint)(__float2int_rn(vals[w*4+1] * inv) + 128);
                uint b2 = (uint)(__float2int_rn(vals[w*4+2] * inv) + 128);
                uint b3 = (uint)(__float2int_rn(vals[w*4+3] * inv) + 128);
                pk[w] = b0 | (b1 << 8) | (b2 << 16) | (b3 << 24);
            }
            int grow = row0 + lrow;
            if (grow < n) {
                char* dst = (char*)kv + (size_t)grow * 512 + 256 + vseg + hh * 32;
                *(uint4*)dst        = make_uint4(pk[0], pk[1], pk[2], pk[3]);
                *(uint4*)(dst + 16) = make_uint4(pk[4], pk[5], pk[6], pk[7]);
                vscale[(size_t)grow * 8 + (vseg >> 5) + hh] = scl;
            }
        }
    } else {
        // q: 128 rows x 256B: 8 passes; 16 lanes = one 256B row segment
        #pragma unroll
        for (int pass = 0; pass < 8; ++pass) {
            int g = pass * 256 + tid;
            int lrow = g >> 4, u = g & 15;
            uint4 d = *(const uint4*)(sb + lrow * 256 + ((u ^ (lrow & 7)) << 4));
            int grow = row0 + lrow;
            if (grow < n)
                *(uint4*)((char*)qb + (size_t)grow * 512 + col0 * 2 + u * 16) = d;
        }
    }
}

// Fused SDDMM + softmax + SpMM. One wave per dst node.
// kv row (512B): k fp8 [0,256) + v uint8 biased [256,512); vscale separate.
__global__ __launch_bounds__(256) void fused_attn(
    const ushort* __restrict__ qb, const uchar* __restrict__ kv,
    const float* __restrict__ vscale, const int* __restrict__ col,
    const int* __restrict__ row_ptr, ushort* __restrict__ agg, int n)
{
    int node = blockIdx.x * 4 + (threadIdx.x >> 6);
    if (node >= n) return;
    int lane = threadIdx.x & 63;
    int p0 = row_ptr[node], p1 = row_ptr[node + 1];

    const int slot = lane >> 4;          // 0..3 edge slot
    const int l16 = lane & 15;           // covers dims [l16*16, l16*16+16)
    const int qoff = l16 * 32;

    float qf[16];
    {
        const char* qbp = (const char*)qb + (size_t)node * 512 + qoff;
        uint4 q0 = *(const uint4*)qbp;
        uint4 q1 = *(const uint4*)(qbp + 16);
        qf[0] = bflo(q0.x); qf[1] = bfhi(q0.x);
        qf[2] = bflo(q0.y); qf[3] = bfhi(q0.y);
        qf[4] = bflo(q0.z); qf[5] = bfhi(q0.z);
        qf[6] = bflo(q0.w); qf[7] = bfhi(q0.w);
        qf[8] = bflo(q1.x); qf[9] = bfhi(q1.x);
        qf[10] = bflo(q1.y); qf[11] = bfhi(q1.y);
        qf[12] = bflo(q1.z); qf[13] = bfhi(q1.z);
        qf[14] = bflo(q1.w); qf[15] = bfhi(q1.w);
    }

    float denom = 0.f;
    float cacc = 0.f;                    // sum of p*scale (for -128 correction)
    float acc[16] = {};

#define ISSUE(IDX, K, V, S)                                                    \
    do {                                                                       \
        int src_ = __shfl(cl, (IDX));                                          \
        const char* b_ = (const char*)kv + (size_t)src_ * 512;                 \
        K = *(const uint4*)(b_ + l16 * 16);                                    \
        V = *(const uint4*)(b_ + 256 + l16 * 16);                              \
        S = vscale[(size_t)src_ * 8 + (l16 >> 1)];                             \
    } while (0)

#define CONSUME(VALID, K, V, S)                                                \
    do {                                                                       \
        float kf_[16];                                                         \
        fp8x4_to_f32(K.x, kf_); fp8x4_to_f32(K.y, kf_ + 4);                    \
        fp8x4_to_f32(K.z, kf_ + 8); fp8x4_to_f32(K.w, kf_ + 12);               \
        float sp_ = 0.f;                                                       \
        _Pragma("unroll")                                                      \
        for (int i_ = 0; i_ < 16; ++i_) sp_ = fmaf(qf[i_], kf_[i_], sp_);      \
        float s_ = sp_ + __shfl_xor(sp_, 1);                                   \
        float p_ = (VALID) ? __expf(s_) : 0.f;                                 \
        denom += p_;                                                           \
        float ps_ = p_ * (S);                                                  \
        cacc += ps_;                                                           \
        uint w_;                                                               \
        w_ = V.x;                                                              \
        acc[0]  = fmaf(ps_, (float)(w_ & 0xff),         acc[0]);               \
        acc[1]  = fmaf(ps_, (float)((w_ >> 8) & 0xff),  acc[1]);               \
        acc[2]  = fmaf(ps_, (float)((w_ >> 16) & 0xff), acc[2]);               \
        acc[3]  = fmaf(ps_, (float)(w_ >> 24),          acc[3]);               \
        w_ = V.y;                                                              \
        acc[4]  = fmaf(ps_, (float)(w_ & 0xff),         acc[4]);               \
        acc[5]  = fmaf(ps_, (float)((w_ >> 8) & 0xff),  acc[5]);               \
        acc[6]  = fmaf(ps_, (float)((w_ >> 16) & 0xff), acc[6]);               \
        acc[7]  = fmaf(ps_, (float)(w_ >> 24),          acc[7]);               \
        w_ = V.z;                                                              \
        acc[8]  = fmaf(ps_, (float)(w_ & 0xff),         acc[8]);               \
        acc[9]  = fmaf(ps_, (float)((w_ >> 8) & 0xff),  acc[9]);               \
        acc[10] = fmaf(ps_, (float)((w_ >> 16) & 0xff), acc[10]);              \
        acc[11] = fmaf(ps_, (float)(w_ >> 24),          acc[11]);              \
        w_ = V.w;                                                              \
        acc[12] = fmaf(ps_, (float)(w_ & 0xff),         acc[12]);              \
        acc[13] = fmaf(ps_, (float)((w_ >> 8) & 0xff),  acc[13]);              \
        acc[14] = fmaf(ps_, (float)((w_ >> 16) & 0xff), acc[14]);              \
        acc[15] = fmaf(ps_, (float)(w_ >> 24),          acc[15]);              \
    } while (0)

    for (int bbase = p0; bbase < p1; bbase += 64) {
        int bd = min(64, p1 - bbase);
        int cl = (lane < bd) ? col[bbase + lane] : 0;
        int nch = (bd + 3) >> 2;

        uint4 kA, vA, kB, vB; float sA, sB;
        ISSUE(slot, kA, vA, sA);
        int c = 0;
        for (;;) {
            if (c + 1 < nch) ISSUE((c + 1) * 4 + slot, kB, vB, sB);
            CONSUME(c * 4 + slot < bd, kA, vA, sA);
            if (++c >= nch) break;
            if (c + 1 < nch) ISSUE((c + 1) * 4 + slot, kA, vA, sA);
            CONSUME(c * 4 + slot < bd, kB, vB, sB);
            if (++c >= nch) break;
        }
    }
#undef ISSUE
#undef CONSUME

    // undo the +128 bias, then reduce over the 4 slots
    #pragma unroll
    for (int i = 0; i < 16; ++i) acc[i] = fmaf(-128.f, cacc, acc[i]);
    #pragma unroll
    for (int i = 0; i < 16; ++i) {
        acc[i] += __shfl_xor(acc[i], 16);
        acc[i] += __shfl_xor(acc[i], 32);
    }
    denom += __shfl_xor(denom, 16);
    denom += __shfl_xor(denom, 32);

    if (slot == 0) {
        float inv = denom > 0.f ? 1.f / denom : 0.f;
        uint o[8];
        #pragma unroll
        for (int i = 0; i < 8; ++i)
            o[i] = (uint)f2bf(acc[2 * i] * inv) |
                   ((uint)f2bf(acc[2 * i + 1] * inv) << 16);
        char* ob = (char*)agg + (size_t)node * 512 + qoff;
        *(uint4*)ob        = make_uint4(o[0], o[1], o[2], o[3]);
        *(uint4*)(ob + 16) = make_uint4(o[4], o[5], o[6], o[7]);
    }
}

extern "C" void kernel_launch(void* const* d_in, const int* in_sizes, int n_in,
                              void* d_out, int out_size, void* d_ws, size_t ws_size,
                              hipStream_t stream)
{
    const float* h  = (const float*)d_in[0];
    const int*   row = (const int*)d_in[1];
    const int*   col = (const int*)d_in[2];
    const float* Wq = (const float*)d_in[3];
    const float* bq = (const float*)d_in[4];
    const float* Wk = (const float*)d_in[5];
    const float* bk = (const float*)d_in[6];
    const float* Wv = (const float*)d_in[7];
    const float* bv = (const float*)d_in[8];
    const float* Wo = (const float*)d_in[9];
    const float* bo = (const float*)d_in[10];
    float* out = (float*)d_out;

    const int n = in_sizes[0] / 256;
    const int E = in_sizes[1];
    const size_t NC = (size_t)n * 256;

    char* base = (char*)d_ws;
    ushort* qbb    = (ushort*)(base);                            // NC*2 B
    uchar*  kv     = (uchar*)(base + NC * 2);                    // n*512 B
    float*  vscale = (float*)(base + NC * 4);                    // n*32 B
    ushort* aggb   = (ushort*)(base + NC * 4 + (size_t)n * 32);  // NC*2
    ushort* hb     = (ushort*)(base + NC * 6 + (size_t)n * 32);  // NC*2
    ushort* Wall   = (ushort*)(base + NC * 8 + (size_t)n * 32);  // 384KB
    ushort* Wot    = Wall + 768 * 256;                           // 128KB
    float*  ball   = (float*)(Wot + 65536);                      // 3KB
    int* row_ptr   = (int*)(ball + 768);

    const float scaling = 0.17677669529663687f;  // 32^-0.5

    dim3 blk(256);
    prep<<<dim3(257, 5), blk, 0, stream>>>(Wq, Wk, Wv, Wo, bq, bk, bv,
                                           row, row_ptr, n, E,
                                           Wall, Wot, ball);
    convert_bf16<<<dim3((int)((NC / 4 + 255) / 256)), blk, 0, stream>>>(h, hb, NC);

    const int mtiles = (n + 127) / 128;
    gemm_mfma_lds<0><<<dim3(6, mtiles), blk, 0, stream>>>(
        hb, Wall, ball, qbb, kv, vscale, nullptr, n, scaling);

    fused_attn<<<dim3((n + 3) / 4), blk, 0, stream>>>(
        qbb, kv, vscale, col, row_ptr, aggb, n);

    gemm_mfma_lds<1><<<dim3(2, mtiles), blk, 0, stream>>>(
        aggb, Wot, bo, nullptr, nullptr, nullptr, out, n, 1.f);
}

// Round 14
// 155.600 us; speedup vs baseline: 1.0713x; 1.0084x over previous
//
#include <hip/hip_runtime.h>
#include <math.h>

// ---------------------------------------------------------------------------
// SparseMHA, round 14:
//   prep: W^T bf16 + bias concat + CSR row_ptr (1 kernel)
//   convert_bf16: h -> hb
//   gemm<0>: hb via global_load_lds ->
//     qb8[n][256]  int8 signed (scaled q), qscale[n][8] f32
//     kv[n][512]:  k int8 signed [0,256) + v uint8 biased [256,512)
//     kscale[n][2] f32 (per src half: heads 0-3 / 4-7), vscale[n][8] f32
//   fused_attn: scores via sdot4 (int8 q.k), v int8 dequant w/ correction
//   gemm<1>: out = aggb @ Wo + bo (f32)
// ---------------------------------------------------------------------------

typedef __attribute__((ext_vector_type(8))) short bf16x8;
typedef __attribute__((ext_vector_type(4))) float f32x4;

__device__ __forceinline__ ushort f2bf(float f) {           // RNE f32->bf16
    uint u = __float_as_uint(f);
    u += 0x7fffu + ((u >> 16) & 1u);
    return (ushort)(u >> 16);
}
__device__ __forceinline__ float bflo(uint u) { return __uint_as_float(u << 16); }
__device__ __forceinline__ float bfhi(uint u) { return __uint_as_float(u & 0xffff0000u); }

#if __has_builtin(__builtin_amdgcn_sdot4)
__device__ __forceinline__ int SDOT4(uint a, uint b, int c) {
    return __builtin_amdgcn_sdot4((int)a, (int)b, c, false);
}
#else
__device__ __forceinline__ int SDOT4(uint a, uint b, int c) {
    #pragma unroll
    for (int i = 0; i < 4; ++i)
        c += ((int)(a << (24 - 8 * i)) >> 24) * ((int)(b << (24 - 8 * i)) >> 24);
    return c;
}
#endif

__device__ __forceinline__ void load_lds16(const void* g, void* l) {
    __builtin_amdgcn_global_load_lds(
        (const __attribute__((address_space(1))) void*)g,
        (__attribute__((address_space(3))) void*)l, 16, 0, 0);
}

// f32 -> bf16 elementwise (h)
__global__ __launch_bounds__(256) void convert_bf16(
    const float* __restrict__ in, ushort* __restrict__ out, size_t nelem)
{
    size_t i = ((size_t)blockIdx.x * 256 + threadIdx.x) * 4;
    if (i >= nelem) return;
    float4 v = *(const float4*)(in + i);
    *(ushort4*)(out + i) = make_ushort4(f2bf(v.x), f2bf(v.y), f2bf(v.z), f2bf(v.w));
}

// All prep in one launch: grid (257, 5).
__global__ __launch_bounds__(256) void prep(
    const float* __restrict__ Wq, const float* __restrict__ Wk,
    const float* __restrict__ Wv, const float* __restrict__ Wo,
    const float* __restrict__ bq, const float* __restrict__ bk,
    const float* __restrict__ bv,
    const int* __restrict__ row, int* __restrict__ row_ptr, int n, int E,
    ushort* __restrict__ Wall, ushort* __restrict__ Wot,
    float* __restrict__ ball)
{
    int m = blockIdx.y;
    if (m == 4) {
        int i = blockIdx.x * 256 + threadIdx.x;
        if (i > n) return;
        int lo = 0, hi = E;
        while (lo < hi) {
            int mid = (lo + hi) >> 1;
            if (row[mid] < i) lo = mid + 1; else hi = mid;
        }
        row_ptr[i] = lo;
        return;
    }
    if (blockIdx.x < 256) {
        int idx = blockIdx.x * 256 + threadIdx.x;   // idx = k*256 + nn
        int k = idx >> 8, nn = idx & 255;
        if (m < 3) {
            const float* W = m == 0 ? Wq : (m == 1 ? Wk : Wv);
            Wall[((size_t)m * 256 + nn) * 256 + k] = f2bf(W[idx]);
        } else {
            Wot[nn * 256 + k] = f2bf(Wo[idx]);
        }
    } else if (m < 3) {
        int i = threadIdx.x;
        ball[m * 256 + i] = (m == 0 ? bq : (m == 1 ? bk : bv))[i];
    }
}

// ---------------------------------------------------------------------------
// LDS-staged MFMA GEMM (m97 structure), 128x128 tiles, grid (6|2, mtiles).
// MODE 0 (QKV): tiles 0,1 -> q int8+qscale; 2,3 -> k int8+kscale;
//               4,5 -> v uint8+vscale. Epilogue via LDS bounce (bf16 pack).
// MODE 1 (out): f32 direct stores.
// ---------------------------------------------------------------------------
template<int MODE>
__global__ __launch_bounds__(256) void gemm_mfma_lds(
    const ushort* __restrict__ A, const ushort* __restrict__ Wt,
    const float* __restrict__ bias, char* __restrict__ qb8,
    float* __restrict__ qscale, uchar* __restrict__ kv,
    float* __restrict__ kscale, float* __restrict__ vscale,
    float* __restrict__ outf, int n, float scale)
{
    __shared__ ushort SH[2 * 128 * 64];          // As | Bs, reused by epilogue
    ushort* As = SH;
    ushort* Bs = SH + 128 * 64;

    const int nwg = gridDim.x * gridDim.y;
    const int orig = blockIdx.y * gridDim.x + blockIdx.x;
    const int xcd = orig & 7, rnd = orig >> 3;
    const int q8 = nwg >> 3, r8 = nwg & 7;
    const int wgid = (xcd < r8 ? xcd * (q8 + 1) : r8 * (q8 + 1) + (xcd - r8) * q8) + rnd;
    const int tx = wgid % gridDim.x;
    const int ty = wgid / gridDim.x;

    const int tid = threadIdx.x;
    const int lane = tid & 63;
    const int wave = tid >> 6;
    const int col0 = tx * 128;
    const int row0 = ty * 128;
    const int fr = lane & 15;
    const int kg = lane >> 4;
    const int wr = (wave >> 1) * 64;
    const int wc = (wave & 1) * 64;

    f32x4 acc[4][4] = {};

    const int srow = tid >> 3;
    const int sc8 = tid & 7;

    for (int kt = 0; kt < 4; ++kt) {
        #pragma unroll
        for (int it = 0; it < 4; ++it) {
            int r = srow + it * 32;
            int chunk = sc8 ^ (r & 7);
            int ar = row0 + r; ar = ar < n ? ar : n - 1;
            load_lds16((const char*)A + (size_t)ar * 512 + kt * 128 + chunk * 16,
                       (char*)As + (it * 256 + tid) * 16);
            load_lds16((const char*)Wt + (size_t)(col0 + r) * 512 + kt * 128 + chunk * 16,
                       (char*)Bs + (it * 256 + tid) * 16);
        }
        __syncthreads();

        #pragma unroll
        for (int ks = 0; ks < 2; ++ks) {
            bf16x8 a[4], b[4];
            #pragma unroll
            for (int i = 0; i < 4; ++i) {
                int r = wr + i * 16 + fr;
                int chunk = (ks * 4 + kg) ^ (r & 7);
                a[i] = *(const bf16x8*)((const char*)As + r * 128 + chunk * 16);
            }
            #pragma unroll
            for (int j = 0; j < 4; ++j) {
                int c = wc + j * 16 + fr;
                int chunk = (ks * 4 + kg) ^ (c & 7);
                b[j] = *(const bf16x8*)((const char*)Bs + c * 128 + chunk * 16);
            }
            #pragma unroll
            for (int i = 0; i < 4; ++i)
                #pragma unroll
                for (int j = 0; j < 4; ++j)
                    acc[i][j] = __builtin_amdgcn_mfma_f32_16x16x32_bf16(
                        a[i], b[j], acc[i][j], 0, 0, 0);
        }
        __syncthreads();
    }

    if constexpr (MODE == 1) {
        #pragma unroll
        for (int j = 0; j < 4; ++j) {
            int gcol = col0 + wc + j * 16 + fr;
            float bj = bias[gcol];
            #pragma unroll
            for (int i = 0; i < 4; ++i) {
                #pragma unroll
                for (int r = 0; r < 4; ++r) {
                    int grow = row0 + wr + i * 16 + kg * 4 + r;
                    if (grow >= n) continue;
                    outf[(size_t)grow * 256 + gcol] = acc[i][j][r] + bj;
                }
            }
        }
        return;
    }

    // ---- MODE 0 epilogue: pack bf16 to LDS (256B rows, unit-swizzled) ----
    char* sb = (char*)SH;
    const float sc = (col0 < 256) ? scale : 1.f;

    #pragma unroll
    for (int j = 0; j < 4; ++j) {
        int cw = wc + j * 16 + fr;                   // local col 0..127
        float bj = bias[col0 + cw];
        #pragma unroll
        for (int i = 0; i < 4; ++i) {
            #pragma unroll
            for (int r2 = 0; r2 < 4; ++r2) {
                int lrow = wr + i * 16 + kg * 4 + r2;
                float val = (acc[i][j][r2] + bj) * sc;
                int u = cw >> 3;
                *(ushort*)(sb + lrow * 256 + ((u ^ (lrow & 7)) << 4) +
                           ((cw & 7) << 1)) = f2bf(val);
            }
        }
    }
    __syncthreads();

    if (col0 >= 256 && col0 < 512) {
        // k tiles: signed int8, per-(row, 128-col half) scale.
        int kseg = col0 - 256;                       // 0 or 128
        int khalf = kseg >> 7;                       // 0 or 1
        #pragma unroll
        for (int pass = 0; pass < 2; ++pass) {
            int t = pass * 256 + tid;
            int lrow = t >> 2, sub = t & 3;
            float vals[32];
            #pragma unroll
            for (int uu = 0; uu < 4; ++uu) {
                int u = sub * 4 + uu;
                uint4 d = *(const uint4*)(sb + lrow * 256 + ((u ^ (lrow & 7)) << 4));
                vals[uu*8+0] = bflo(d.x); vals[uu*8+1] = bfhi(d.x);
                vals[uu*8+2] = bflo(d.y); vals[uu*8+3] = bfhi(d.y);
                vals[uu*8+4] = bflo(d.z); vals[uu*8+5] = bfhi(d.z);
                vals[uu*8+6] = bflo(d.w); vals[uu*8+7] = bfhi(d.w);
            }
            float mx = 0.f;
            #pragma unroll
            for (int i = 0; i < 32; ++i) mx = fmaxf(mx, fabsf(vals[i]));
            mx = fmaxf(mx, __shfl_xor(mx, 1));
            mx = fmaxf(mx, __shfl_xor(mx, 2));       // row max over 128 cols
            float inv = mx > 0.f ? 127.f / mx : 0.f;
            float scl = mx > 0.f ? mx * (1.f / 127.f) : 0.f;
            uint pk[8];
            #pragma unroll
            for (int w = 0; w < 8; ++w) {
                uint b0 = (uint)__float2int_rn(vals[w*4+0] * inv) & 0xff;
                uint b1 = (uint)__float2int_rn(vals[w*4+1] * inv) & 0xff;
                uint b2 = (uint)__float2int_rn(vals[w*4+2] * inv) & 0xff;
                uint b3 = (uint)__float2int_rn(vals[w*4+3] * inv) & 0xff;
                pk[w] = b0 | (b1 << 8) | (b2 << 16) | (b3 << 24);
            }
            int grow = row0 + lrow;
            if (grow < n) {
                char* dst = (char*)kv + (size_t)grow * 512 + kseg + sub * 32;
                *(uint4*)dst        = make_uint4(pk[0], pk[1], pk[2], pk[3]);
                *(uint4*)(dst + 16) = make_uint4(pk[4], pk[5], pk[6], pk[7]);
                if (sub == 0) kscale[(size_t)grow * 2 + khalf] = scl;
            }
        }
    } else {
        // q tiles (signed -> qb8+qscale) and v tiles (biased -> kv+vscale)
        const bool isq = (col0 < 256);
        int seg = isq ? col0 : (col0 - 512);         // 0 or 128
        #pragma unroll
        for (int pass = 0; pass < 2; ++pass) {
            int t = pass * 256 + tid;
            int lrow = t >> 2, hh = t & 3;
            float vals[32];
            #pragma unroll
            for (int uu = 0; uu < 4; ++uu) {
                int u = hh * 4 + uu;
                uint4 d = *(const uint4*)(sb + lrow * 256 + ((u ^ (lrow & 7)) << 4));
                vals[uu*8+0] = bflo(d.x); vals[uu*8+1] = bfhi(d.x);
                vals[uu*8+2] = bflo(d.y); vals[uu*8+3] = bfhi(d.y);
                vals[uu*8+4] = bflo(d.z); vals[uu*8+5] = bfhi(d.z);
                vals[uu*8+6] = bflo(d.w); vals[uu*8+7] = bfhi(d.w);
            }
            float mx = 0.f;
            #pragma unroll
            for (int i = 0; i < 32; ++i) mx = fmaxf(mx, fabsf(vals[i]));
            float inv = mx > 0.f ? 127.f / mx : 0.f;
            float scl = mx > 0.f ? mx * (1.f / 127.f) : 0.f;
            uint pk[8];
            #pragma unroll
            for (int w = 0; w < 8; ++w) {
                int b0 = __float2int_rn(vals[w*4+0] * inv);
                int b1 = __float2int_rn(vals[w*4+1] * inv);
                int b2 = __float2int_rn(vals[w*4+2] * inv);
                int b3 = __float2int_rn(vals[w*4+3] * inv);
                if (!isq) { b0 += 128; b1 += 128; b2 += 128; b3 += 128; }
                pk[w] = ((uint)b0 & 0xff) | (((uint)b1 & 0xff) << 8) |
                        (((uint)b2 & 0xff) << 16) | (((uint)b3 & 0xff) << 24);
            }
            int grow = row0 + lrow;
            if (grow < n) {
                char* dst = isq ? (qb8 + (size_t)grow * 256 + seg + hh * 32)
                                : ((char*)kv + (size_t)grow * 512 + 256 + seg + hh * 32);
                *(uint4*)dst        = make_uint4(pk[0], pk[1], pk[2], pk[3]);
                *(uint4*)(dst + 16) = make_uint4(pk[4], pk[5], pk[6], pk[7]);
                float* sdst = isq ? qscale : vscale;
                sdst[(size_t)grow * 8 + (seg >> 5) + hh] = scl;
            }
        }
    }
}

// Fused SDDMM + softmax + SpMM. One wave per dst node.
// kv row (512B): k int8 signed [0,256) + v uint8 biased [256,512).
__global__ __launch_bounds__(256) void fused_attn(
    const char* __restrict__ qb8, const float* __restrict__ qscale,
    const uchar* __restrict__ kv, const float* __restrict__ kscale,
    const float* __restrict__ vscale, const int* __restrict__ col,
    const int* __restrict__ row_ptr, ushort* __restrict__ agg, int n)
{
    int node = blockIdx.x * 4 + (threadIdx.x >> 6);
    if (node >= n) return;
    int lane = threadIdx.x & 63;
    int p0 = row_ptr[node], p1 = row_ptr[node + 1];

    const int slot = lane >> 4;          // 0..3 edge slot
    const int l16 = lane & 15;           // covers dims [l16*16, l16*16+16)
    const int aoff = l16 * 32;           // byte offset into 512B bf16 agg row

    uint4 qi = *(const uint4*)(qb8 + (size_t)node * 256 + l16 * 16);
    float qs = qscale[(size_t)node * 8 + (l16 >> 1)];

    float denom = 0.f;
    float cacc = 0.f;                    // sum of p*vscale (-128 correction)
    float acc[16] = {};

#define ISSUE(IDX, K, V, KS, VS)                                               \
    do {                                                                       \
        int src_ = __shfl(cl, (IDX));                                          \
        const char* b_ = (const char*)kv + (size_t)src_ * 512;                 \
        K = *(const uint4*)(b_ + l16 * 16);                                    \
        V = *(const uint4*)(b_ + 256 + l16 * 16);                              \
        KS = kscale[(size_t)src_ * 2 + (l16 >> 3)];                            \
        VS = vscale[(size_t)src_ * 8 + (l16 >> 1)];                            \
    } while (0)

#define CONSUME(VALID, K, V, KS, VS)                                           \
    do {                                                                       \
        int id_ = SDOT4(qi.x, K.x, 0);                                         \
        id_ = SDOT4(qi.y, K.y, id_);                                           \
        id_ = SDOT4(qi.z, K.z, id_);                                           \
        id_ = SDOT4(qi.w, K.w, id_);                                           \
        int it_ = id_ + __shfl_xor(id_, 1);                                    \
        float s_ = (float)it_ * (qs * (KS));                                   \
        float p_ = (VALID) ? __expf(s_) : 0.f;                                 \
        denom += p_;                                                           \
        float ps_ = p_ * (VS);                                                 \
        cacc += ps_;                                                           \
        uint w_;                                                               \
        w_ = V.x;                                                              \
        acc[0]  = fmaf(ps_, (float)(w_ & 0xff),         acc[0]);               \
        acc[1]  = fmaf(ps_, (float)((w_ >> 8) & 0xff),  acc[1]);               \
        acc[2]  = fmaf(ps_, (float)((w_ >> 16) & 0xff), acc[2]);               \
        acc[3]  = fmaf(ps_, (float)(w_ >> 24),          acc[3]);               \
        w_ = V.y;                                                              \
        acc[4]  = fmaf(ps_, (float)(w_ & 0xff),         acc[4]);               \
        acc[5]  = fmaf(ps_, (float)((w_ >> 8) & 0xff),  acc[5]);               \
        acc[6]  = fmaf(ps_, (float)((w_ >> 16) & 0xff), acc[6]);               \
        acc[7]  = fmaf(ps_, (float)(w_ >> 24),          acc[7]);               \
        w_ = V.z;                                                              \
        acc[8]  = fmaf(ps_, (float)(w_ & 0xff),         acc[8]);               \
        acc[9]  = fmaf(ps_, (float)((w_ >> 8) & 0xff),  acc[9]);               \
        acc[10] = fmaf(ps_, (float)((w_ >> 16) & 0xff), acc[10]);              \
        acc[11] = fmaf(ps_, (float)(w_ >> 24),          acc[11]);              \
        w_ = V.w;                                                              \
        acc[12] = fmaf(ps_, (float)(w_ & 0xff),         acc[12]);              \
        acc[13] = fmaf(ps_, (float)((w_ >> 8) & 0xff),  acc[13]);              \
        acc[14] = fmaf(ps_, (float)((w_ >> 16) & 0xff), acc[14]);              \
        acc[15] = fmaf(ps_, (float)(w_ >> 24),          acc[15]);              \
    } while (0)

    for (int bbase = p0; bbase < p1; bbase += 64) {
        int bd = min(64, p1 - bbase);
        int cl = (lane < bd) ? col[bbase + lane] : 0;
        int nch = (bd + 3) >> 2;

        uint4 kA, vA, kB, vB; float ksA, vsA, ksB, vsB;
        ISSUE(slot, kA, vA, ksA, vsA);
        int c = 0;
        for (;;) {
            if (c + 1 < nch) ISSUE((c + 1) * 4 + slot, kB, vB, ksB, vsB);
            CONSUME(c * 4 + slot < bd, kA, vA, ksA, vsA);
            if (++c >= nch) break;
            if (c + 1 < nch) ISSUE((c + 1) * 4 + slot, kA, vA, ksA, vsA);
            CONSUME(c * 4 + slot < bd, kB, vB, ksB, vsB);
            if (++c >= nch) break;
        }
    }
#undef ISSUE
#undef CONSUME

    #pragma unroll
    for (int i = 0; i < 16; ++i) acc[i] = fmaf(-128.f, cacc, acc[i]);
    #pragma unroll
    for (int i = 0; i < 16; ++i) {
        acc[i] += __shfl_xor(acc[i], 16);
        acc[i] += __shfl_xor(acc[i], 32);
    }
    denom += __shfl_xor(denom, 16);
    denom += __shfl_xor(denom, 32);

    if (slot == 0) {
        float inv = denom > 0.f ? 1.f / denom : 0.f;
        uint o[8];
        #pragma unroll
        for (int i = 0; i < 8; ++i)
            o[i] = (uint)f2bf(acc[2 * i] * inv) |
                   ((uint)f2bf(acc[2 * i + 1] * inv) << 16);
        char* ob = (char*)agg + (size_t)node * 512 + aoff;
        *(uint4*)ob        = make_uint4(o[0], o[1], o[2], o[3]);
        *(uint4*)(ob + 16) = make_uint4(o[4], o[5], o[6], o[7]);
    }
}

extern "C" void kernel_launch(void* const* d_in, const int* in_sizes, int n_in,
                              void* d_out, int out_size, void* d_ws, size_t ws_size,
                              hipStream_t stream)
{
    const float* h  = (const float*)d_in[0];
    const int*   row = (const int*)d_in[1];
    const int*   col = (const int*)d_in[2];
    const float* Wq = (const float*)d_in[3];
    const float* bq = (const float*)d_in[4];
    const float* Wk = (const float*)d_in[5];
    const float* bk = (const float*)d_in[6];
    const float* Wv = (const float*)d_in[7];
    const float* bv = (const float*)d_in[8];
    const float* Wo = (const float*)d_in[9];
    const float* bo = (const float*)d_in[10];
    float* out = (float*)d_out;

    const int n = in_sizes[0] / 256;
    const int E = in_sizes[1];
    const size_t NC = (size_t)n * 256;

    char* base = (char*)d_ws;
    char*   qb8    = base;                                        // n*256 B
    uchar*  kv     = (uchar*)(base + (size_t)n * 256);            // n*512 B
    float*  qscale = (float*)(base + (size_t)n * 768);            // n*32 B
    float*  vscale = (float*)(base + (size_t)n * 800);            // n*32 B
    float*  kscale = (float*)(base + (size_t)n * 832);            // n*8 B
    ushort* aggb   = (ushort*)(base + (size_t)n * 840);           // n*512 B
    ushort* hb     = (ushort*)(base + (size_t)n * 1352);          // n*512 B
    ushort* Wall   = (ushort*)(base + (size_t)n * 1864);          // 384KB
    ushort* Wot    = Wall + 768 * 256;                            // 128KB
    float*  ball   = (float*)(Wot + 65536);                       // 3KB
    int* row_ptr   = (int*)(ball + 768);

    const float scaling = 0.17677669529663687f;  // 32^-0.5

    dim3 blk(256);
    prep<<<dim3(257, 5), blk, 0, stream>>>(Wq, Wk, Wv, Wo, bq, bk, bv,
                                           row, row_ptr, n, E,
                                           Wall, Wot, ball);
    convert_bf16<<<dim3((int)((NC / 4 + 255) / 256)), blk, 0, stream>>>(h, hb, NC);

    const int mtiles = (n + 127) / 128;
    gemm_mfma_lds<0><<<dim3(6, mtiles), blk, 0, stream>>>(
        hb, Wall, ball, qb8, qscale, kv, kscale, vscale, nullptr, n, scaling);

    fused_attn<<<dim3((n + 3) / 4), blk, 0, stream>>>(
        qb8, qscale, kv, kscale, vscale, col, row_ptr, aggb, n);

    gemm_mfma_lds<1><<<dim3(2, mtiles), blk, 0, stream>>>(
        aggb, Wot, bo, nullptr, nullptr, nullptr, nullptr, nullptr, out, n, 1.f);
}